// Round 1
// baseline (1231.186 us; speedup 1.0000x reference)
//
#include <hip/hip_runtime.h>
#include <hip/hip_bf16.h>
#include <cfloat>
#include <math.h>

// Problem constants
#define S_LEN 1024
#define DIM 512
#define H_N 8
#define DH 64
#define CB 32
#define NB 32           // S/CB
#define NSEL 4
#define NMEM 4
#define WIN 64
#define CD 2048         // CB*DH
#define SCALE 0.125f    // DH^-0.5
#define EPS 1.1920929e-07f

// ---------------- ws layout (float offsets) ----------------
#define OFF_X      0u
#define OFF_QKV    524288u     // 1024*1536
#define OFF_RQ     2097152u
#define OFF_RK     2621440u
#define OFF_COS    3145728u    // 1024*32
#define OFF_SIN    3178496u
#define OFF_TK     3211264u    // 256*2048
#define OFF_TV     3735552u
#define OFF_HK     4259840u
#define OFF_HV     4784128u
#define OFF_CKC    5308416u    // 256*64
#define OFF_CVC    5324800u
#define OFF_CK     5341184u    // 8*36*64
#define OFF_CV     5359616u
#define OFF_COUT   5378048u    // 1024*512
#define OFF_FOUT   5902336u
#define OFF_SOUT   6426624u
#define OFF_STRAT  6950912u    // 1024*24
#define OFF_ATT    6975488u
#define OFF_SEL    7499776u    // ints: 8*1024*8

// ---------------- RMSNorm ----------------
__global__ void rmsnorm_k(const float* __restrict__ inp, const float* __restrict__ g,
                          float* __restrict__ x) {
    int s = blockIdx.x;
    int t = threadIdx.x;
    float v0 = inp[s * DIM + t];
    float v1 = inp[s * DIM + t + 256];
    float ss = v0 * v0 + v1 * v1;
    // wave reduce
    for (int o = 32; o > 0; o >>= 1) ss += __shfl_xor(ss, o);
    __shared__ float wsum[4];
    int wid = t >> 6, lane = t & 63;
    if (lane == 0) wsum[wid] = ss;
    __syncthreads();
    float tot = wsum[0] + wsum[1] + wsum[2] + wsum[3];
    float scale = 1.0f / sqrtf(tot / (float)DIM + EPS);
    x[s * DIM + t]       = v0 * scale * g[t];
    x[s * DIM + t + 256] = v1 * scale * g[t + 256];
}

// ---------------- RoPE cos/sin table (double precision) ----------------
__global__ void rope_table_k(float* __restrict__ cost, float* __restrict__ sint) {
    int idx = blockIdx.x * 256 + threadIdx.x;   // 1024*32
    int s = idx >> 5, i = idx & 31;
    double inv = pow(10000.0, -(double)(2 * i) / 64.0);
    double ang = (double)s * inv;
    cost[idx] = (float)cos(ang);
    sint[idx] = (float)sin(ang);
}

// ---------------- RoPE apply to q,k ----------------
__global__ void rope_apply_k(const float* __restrict__ qkv, const float* __restrict__ cost,
                             const float* __restrict__ sint,
                             float* __restrict__ rq, float* __restrict__ rk) {
    int idx = blockIdx.x * 256 + threadIdx.x;   // 1024*8*32 pairs
    int s = idx >> 8;
    int rem = idx & 255;
    int h = rem >> 5, i = rem & 31;
    float c = cost[s * 32 + i], sn = sint[s * 32 + i];
    int qb = s * 1536 + h * 64 + 2 * i;
    float q0 = qkv[qb], q1 = qkv[qb + 1];
    int ob = s * 512 + h * 64 + 2 * i;
    rq[ob]     = q0 * c - q1 * sn;
    rq[ob + 1] = q1 * c + q0 * sn;
    float k0 = qkv[qb + 512], k1 = qkv[qb + 513];
    rk[ob]     = k0 * c - k1 * sn;
    rk[ob + 1] = k1 * c + k0 * sn;
}

// ---------------- strategy gates ----------------
__global__ void strat_k(const float* __restrict__ x, const float* __restrict__ sw,
                        const float* __restrict__ sb, float* __restrict__ strat) {
    int s = blockIdx.x;
    int lane = threadIdx.x;
    if (lane < 24) {
        float acc = sb[lane];
        const float* xr = x + s * DIM;
        for (int k = 0; k < DIM; ++k) acc += xr[k] * sw[k * 24 + lane];
        strat[s * 24 + lane] = 1.0f / (1.0f + expf(-acc));
    }
}

// ---------------- build compress-MLP inputs (k/v blocks + positional) ----------------
__global__ void tkv_k(const float* __restrict__ qkv, const float* __restrict__ k_pos,
                      const float* __restrict__ v_pos,
                      float* __restrict__ tk, float* __restrict__ tv) {
    int idx = blockIdx.x * 256 + threadIdx.x;   // 256*2048
    int row = idx >> 11;          // h*32+nb
    int c = idx & 2047;           // cb*64+d
    int h = row >> 5, nb = row & 31;
    int cb = c >> 6, d = c & 63;
    int srow = nb * 32 + cb;
    tk[idx] = qkv[srow * 1536 + 512 + h * 64 + d] + k_pos[(h * 32 + cb) * 64 + d];
    tv[idx] = qkv[srow * 1536 + 1024 + h * 64 + d] + v_pos[(h * 32 + cb) * 64 + d];
}

// ---------------- tiled f32 GEMM: C = A(MxK) @ B(KxN) (+bias, opt relu) ----------------
template <bool RELU>
__global__ void gemm64_k(const float* __restrict__ A, const float* __restrict__ B,
                         const float* __restrict__ bias, float* __restrict__ C,
                         int M, int N, int K) {
    __shared__ float As[16][65];
    __shared__ float Bs[16][65];
    int bm = blockIdx.x * 64, bn = blockIdx.y * 64;
    int tid = threadIdx.x;
    int tx = tid & 15, ty = tid >> 4;
    float acc[4][4] = {};
    for (int k0 = 0; k0 < K; k0 += 16) {
        for (int e = tid; e < 1024; e += 256) {
            int m = e >> 4, kk = e & 15;
            As[kk][m] = A[(bm + m) * K + k0 + kk];
            int kb = e >> 6, n = e & 63;
            Bs[kb][n] = B[(k0 + kb) * N + bn + n];
        }
        __syncthreads();
        for (int kk = 0; kk < 16; ++kk) {
            float a[4], b[4];
#pragma unroll
            for (int i = 0; i < 4; ++i) a[i] = As[kk][ty * 4 + i];
#pragma unroll
            for (int j = 0; j < 4; ++j) b[j] = Bs[kk][tx * 4 + j];
#pragma unroll
            for (int i = 0; i < 4; ++i)
#pragma unroll
                for (int j = 0; j < 4; ++j) acc[i][j] += a[i] * b[j];
        }
        __syncthreads();
    }
#pragma unroll
    for (int i = 0; i < 4; ++i)
#pragma unroll
        for (int j = 0; j < 4; ++j) {
            int m = bm + ty * 4 + i, n = bn + tx * 4 + j;
            float val = acc[i][j] + (bias ? bias[n] : 0.0f);
            if (RELU) val = fmaxf(val, 0.0f);
            C[m * N + n] = val;
        }
}

// ---------------- skinny GEMM: C(Mx64) = A(MxK) @ B(Kx64) + bias ----------------
__global__ void gemm_skinny_k(const float* __restrict__ A, const float* __restrict__ B,
                              const float* __restrict__ bias, float* __restrict__ C, int K) {
    int row = blockIdx.x;
    int col = threadIdx.x & 63;
    int chunk = threadIdx.x >> 6;   // 0..3
    int kpc = K >> 2;
    const float* a = A + row * K + chunk * kpc;
    const float* b = B + chunk * kpc * 64;
    float acc = 0.0f;
    for (int k = 0; k < kpc; ++k) acc += a[k] * b[k * 64 + col];
    __shared__ float red[4][64];
    red[chunk][col] = acc;
    __syncthreads();
    if (chunk == 0) {
        float v = red[0][col] + red[1][col] + red[2][col] + red[3][col] + bias[col];
        C[row * 64 + col] = v;
    }
}

// ---------------- assemble ck/cv with memory slots ----------------
__global__ void ckfill_k(const float* __restrict__ ckc, const float* __restrict__ cvc,
                         const float* __restrict__ mem_kv,
                         float* __restrict__ ck, float* __restrict__ cv) {
    int idx = blockIdx.x * 256 + threadIdx.x;   // 8*36*64
    if (idx >= 8 * 36 * 64) return;
    int h = idx / (36 * 64);
    int r = (idx >> 6) % 36;
    int d = idx & 63;
    if (r < NMEM) {
        ck[idx] = mem_kv[h * 256 + r * 64 + d];
        cv[idx] = mem_kv[2048 + h * 256 + r * 64 + d];
    } else {
        ck[idx] = ckc[(h * 32 + r - 4) * 64 + d];
        cv[idx] = cvc[(h * 32 + r - 4) * 64 + d];
    }
}

// ---------------- compressed attention + fused top-k ----------------
__global__ void comp_attn_k(const float* __restrict__ qkv, const float* __restrict__ ck,
                            const float* __restrict__ cv, float* __restrict__ c_out,
                            int* __restrict__ sel) {
    int s = blockIdx.x, h = blockIdx.y, lane = threadIdx.x;
    __shared__ float qs[64];
    __shared__ float attns[36];
    qs[lane] = qkv[s * 1536 + h * 64 + lane];
    __syncthreads();
    float sim = -FLT_MAX;
    if (lane < 36) {
        bool valid = (lane < NMEM) || ((lane - NMEM + 1) * CB - 1 < s);
        if (valid) {
            const float* kr = ck + (h * 36 + lane) * 64;
            float acc = 0.0f;
            for (int d = 0; d < 64; ++d) acc += qs[d] * kr[d];
            sim = acc * SCALE;
        }
    }
    float mx = sim;
    for (int o = 32; o > 0; o >>= 1) mx = fmaxf(mx, __shfl_xor(mx, o));
    float e = (sim == -FLT_MAX) ? 0.0f : expf(sim - mx);
    float tot = e;
    for (int o = 32; o > 0; o >>= 1) tot += __shfl_xor(tot, o);
    float a = e / tot;
    if (lane < 36) attns[lane] = a;
    __syncthreads();
    float acc = 0.0f;
    for (int j = 0; j < 36; ++j) acc += attns[j] * cv[(h * 36 + j) * 64 + lane];
    c_out[s * 512 + h * 64 + lane] = acc;
    if (lane == 0) {
        float iv[32];
        for (int j = 0; j < 32; ++j) iv[j] = attns[NMEM + j];
        int* sp = sel + (h * 1024 + s) * 8;
        int mask = 0;
        for (int t = 0; t < NSEL; ++t) {
            int bi = 0; float bv = iv[0];
            for (int j = 1; j < 32; ++j) if (iv[j] > bv) { bv = iv[j]; bi = j; }
            sp[t] = bi;
            if (bv > 1e-10f) mask |= 1 << t;
            iv[bi] = -1.0f;
        }
        sp[4] = mask;
    }
}

// ---------------- fine (selected-block) attention ----------------
__global__ void fine_attn_k(const float* __restrict__ qkv, const float* __restrict__ rq,
                            const float* __restrict__ rk, const int* __restrict__ sel,
                            float* __restrict__ f_out) {
    int s = blockIdx.x, h = blockIdx.y, lane = threadIdx.x;
    __shared__ float qs[64];
    __shared__ float attns[160];
    __shared__ int rows[160];
    qs[lane] = rq[s * 512 + h * 64 + lane];
    __syncthreads();
    const int* sp = sel + (h * 1024 + s) * 8;
    int own = s >> 5, p = s & 31, mask = sp[4];
    float sims[3]; int rws[3];
    float mx = -FLT_MAX;
    for (int r = 0; r < 3; ++r) {
        int kk = lane + 64 * r;
        sims[r] = -FLT_MAX; rws[r] = 0;
        if (kk < 160) {
            int sl = kk >> 5, t = kk & 31;
            int blk = (sl < 4) ? sp[sl] : own;
            bool valid = (sl < 4) ? ((mask >> sl) & 1) : (t <= p);
            int row = blk * 32 + t;
            rws[r] = row;
            if (valid) {
                const float* kr = rk + row * 512 + h * 64;
                float acc = 0.0f;
                for (int d = 0; d < 64; ++d) acc += qs[d] * kr[d];
                sims[r] = acc * SCALE;
            }
        }
        mx = fmaxf(mx, sims[r]);
    }
    for (int o = 32; o > 0; o >>= 1) mx = fmaxf(mx, __shfl_xor(mx, o));
    float lsum = 0.0f, es[3];
    for (int r = 0; r < 3; ++r) {
        es[r] = (sims[r] == -FLT_MAX) ? 0.0f : expf(sims[r] - mx);
        lsum += es[r];
    }
    for (int o = 32; o > 0; o >>= 1) lsum += __shfl_xor(lsum, o);
    for (int r = 0; r < 3; ++r) {
        int kk = lane + 64 * r;
        if (kk < 160) { attns[kk] = es[r] / lsum; rows[kk] = rws[r]; }
    }
    __syncthreads();
    float acc = 0.0f;
    for (int kk = 0; kk < 160; ++kk) {
        float a = attns[kk];
        if (a != 0.0f) acc += a * qkv[rows[kk] * 1536 + 1024 + h * 64 + lane];
    }
    f_out[s * 512 + h * 64 + lane] = acc;
}

// ---------------- sliding-window attention ----------------
__global__ void slide_attn_k(const float* __restrict__ qkv, const float* __restrict__ rq,
                             const float* __restrict__ rk, float* __restrict__ s_out) {
    int s = blockIdx.x, h = blockIdx.y, lane = threadIdx.x;
    __shared__ float qs[64];
    __shared__ float attns[65];
    qs[lane] = rq[s * 512 + h * 64 + lane];
    __syncthreads();
    int lo = (s > WIN) ? s - WIN : 0;
    int cnt = s - lo + 1;   // <= 65
    float sims[2];
    float mx = -FLT_MAX;
    for (int r = 0; r < 2; ++r) {
        int kk = lane + 64 * r;
        sims[r] = -FLT_MAX;
        if (kk < cnt) {
            const float* kr = rk + (lo + kk) * 512 + h * 64;
            float acc = 0.0f;
            for (int d = 0; d < 64; ++d) acc += qs[d] * kr[d];
            sims[r] = acc * SCALE;
        }
        mx = fmaxf(mx, sims[r]);
    }
    for (int o = 32; o > 0; o >>= 1) mx = fmaxf(mx, __shfl_xor(mx, o));
    float lsum = 0.0f, es[2];
    for (int r = 0; r < 2; ++r) {
        es[r] = (sims[r] == -FLT_MAX) ? 0.0f : expf(sims[r] - mx);
        lsum += es[r];
    }
    for (int o = 32; o > 0; o >>= 1) lsum += __shfl_xor(lsum, o);
    for (int r = 0; r < 2; ++r) {
        int kk = lane + 64 * r;
        if (kk < 65) attns[kk] = (kk < cnt) ? es[r] / lsum : 0.0f;
    }
    __syncthreads();
    float acc = 0.0f;
    for (int kk = 0; kk < cnt; ++kk)
        acc += attns[kk] * qkv[(lo + kk) * 1536 + 1024 + h * 64 + lane];
    s_out[s * 512 + h * 64 + lane] = acc;
}

// ---------------- gated combine ----------------
__global__ void combine_k(const float* __restrict__ c_out, const float* __restrict__ f_out,
                          const float* __restrict__ s_out, const float* __restrict__ strat,
                          float* __restrict__ att) {
    int idx = blockIdx.x * 256 + threadIdx.x;   // 1024*512
    int s = idx >> 9;
    int c = idx & 511;
    int h = c >> 6;
    const float* st = strat + s * 24 + h * 3;
    att[idx] = st[0] * c_out[idx] + st[1] * f_out[idx] + st[2] * s_out[idx];
}

extern "C" void kernel_launch(void* const* d_in, const int* in_sizes, int n_in,
                              void* d_out, int out_size, void* d_ws, size_t ws_size,
                              hipStream_t stream) {
    const float* inp     = (const float*)d_in[0];
    const float* norm_g  = (const float*)d_in[1];
    const float* w_qkv   = (const float*)d_in[2];
    const float* k_pos   = (const float*)d_in[3];
    const float* v_pos   = (const float*)d_in[4];
    const float* kc_w1   = (const float*)d_in[5];
    const float* kc_b1   = (const float*)d_in[6];
    const float* kc_w2   = (const float*)d_in[7];
    const float* kc_b2   = (const float*)d_in[8];
    const float* vc_w1   = (const float*)d_in[9];
    const float* vc_b1   = (const float*)d_in[10];
    const float* vc_w2   = (const float*)d_in[11];
    const float* vc_b2   = (const float*)d_in[12];
    const float* mem_kv  = (const float*)d_in[13];
    const float* strat_w = (const float*)d_in[14];
    const float* strat_b = (const float*)d_in[15];
    const float* out_w   = (const float*)d_in[16];
    float* out = (float*)d_out;

    float* ws = (float*)d_ws;
    float* x     = ws + OFF_X;
    float* qkv   = ws + OFF_QKV;
    float* rq    = ws + OFF_RQ;
    float* rk    = ws + OFF_RK;
    float* cost  = ws + OFF_COS;
    float* sint  = ws + OFF_SIN;
    float* tk    = ws + OFF_TK;
    float* tv    = ws + OFF_TV;
    float* hk    = ws + OFF_HK;
    float* hv    = ws + OFF_HV;
    float* ckc   = ws + OFF_CKC;
    float* cvc   = ws + OFF_CVC;
    float* ck    = ws + OFF_CK;
    float* cv    = ws + OFF_CV;
    float* c_out = ws + OFF_COUT;
    float* f_out = ws + OFF_FOUT;
    float* s_out = ws + OFF_SOUT;
    float* strat = ws + OFF_STRAT;
    float* att   = ws + OFF_ATT;
    int*   sel   = (int*)(ws + OFF_SEL);

    rmsnorm_k<<<1024, 256, 0, stream>>>(inp, norm_g, x);
    rope_table_k<<<128, 256, 0, stream>>>(cost, sint);
    gemm64_k<false><<<dim3(16, 24), 256, 0, stream>>>(x, w_qkv, nullptr, qkv, 1024, 1536, 512);
    rope_apply_k<<<1024, 256, 0, stream>>>(qkv, cost, sint, rq, rk);
    strat_k<<<1024, 64, 0, stream>>>(x, strat_w, strat_b, strat);
    tkv_k<<<2048, 256, 0, stream>>>(qkv, k_pos, v_pos, tk, tv);
    gemm64_k<true><<<dim3(4, 32), 256, 0, stream>>>(tk, kc_w1, kc_b1, hk, 256, 2048, 2048);
    gemm64_k<true><<<dim3(4, 32), 256, 0, stream>>>(tv, vc_w1, vc_b1, hv, 256, 2048, 2048);
    gemm_skinny_k<<<256, 256, 0, stream>>>(hk, kc_w2, kc_b2, ckc, 2048);
    gemm_skinny_k<<<256, 256, 0, stream>>>(hv, vc_w2, vc_b2, cvc, 2048);
    ckfill_k<<<72, 256, 0, stream>>>(ckc, cvc, mem_kv, ck, cv);
    comp_attn_k<<<dim3(1024, 8), 64, 0, stream>>>(qkv, ck, cv, c_out, sel);
    fine_attn_k<<<dim3(1024, 8), 64, 0, stream>>>(qkv, rq, rk, sel, f_out);
    slide_attn_k<<<dim3(1024, 8), 64, 0, stream>>>(qkv, rq, rk, s_out);
    combine_k<<<2048, 256, 0, stream>>>(c_out, f_out, s_out, strat, att);
    gemm64_k<false><<<dim3(16, 8), 256, 0, stream>>>(att, out_w, nullptr, out, 1024, 512, 512);
}

// Round 2
// 455.687 us; speedup vs baseline: 2.7018x; 2.7018x over previous
//
#include <hip/hip_runtime.h>
#include <hip/hip_bf16.h>
#include <cfloat>
#include <math.h>

// Problem constants
#define S_LEN 1024
#define DIM 512
#define H_N 8
#define DH 64
#define CB 32
#define NB 32           // S/CB
#define NSEL 4
#define NMEM 4
#define WIN 64
#define CD 2048         // CB*DH
#define SCALE 0.125f    // DH^-0.5
#define EPS 1.1920929e-07f

// ---------------- ws layout (float offsets) ----------------
#define OFF_X      0u
#define OFF_QKV    524288u     // 1024*1536
#define OFF_RQ     2097152u
#define OFF_RK     2621440u
#define OFF_COS    3145728u    // 1024*32
#define OFF_SIN    3178496u
#define OFF_TK     3211264u    // 256*2048
#define OFF_TV     3735552u
#define OFF_HK     4259840u
#define OFF_HV     4784128u
#define OFF_CKC    5308416u    // 256*64
#define OFF_CVC    5324800u
#define OFF_CK     5341184u    // 8*36*64
#define OFF_CV     5359616u
#define OFF_COUT   5378048u    // 1024*512
#define OFF_FOUT   5902336u
#define OFF_SOUT   6426624u
#define OFF_STRAT  6950912u    // 1024*24
#define OFF_ATT    6975488u
#define OFF_SEL    7499776u    // ints: 8*1024*8

// ---------------- RMSNorm + strategy gates (fused) ----------------
__global__ void rmsnorm_strat_k(const float* __restrict__ inp, const float* __restrict__ g,
                                const float* __restrict__ sw, const float* __restrict__ sb,
                                float* __restrict__ x, float* __restrict__ strat) {
    int s = blockIdx.x;
    int t = threadIdx.x;
    __shared__ __align__(16) float xs[512];
    __shared__ float red[24][8];
    float v0 = inp[s * DIM + t];
    float v1 = inp[s * DIM + t + 256];
    float ss = v0 * v0 + v1 * v1;
    for (int o = 32; o > 0; o >>= 1) ss += __shfl_xor(ss, o);
    __shared__ float wsum[4];
    int wid = t >> 6, lane = t & 63;
    if (lane == 0) wsum[wid] = ss;
    __syncthreads();
    float tot = wsum[0] + wsum[1] + wsum[2] + wsum[3];
    float scale = 1.0f / sqrtf(tot / (float)DIM + EPS);
    float x0 = v0 * scale * g[t];
    float x1 = v1 * scale * g[t + 256];
    x[s * DIM + t]       = x0;
    x[s * DIM + t + 256] = x1;
    xs[t] = x0;
    xs[t + 256] = x1;
    __syncthreads();
    // strat: 24 outputs, 8 partial-threads each (t<192)
    if (t < 192) {
        int o = t >> 3, p = t & 7;
        float acc = 0.0f;
        const float* xb = xs + p * 64;
        for (int k = 0; k < 64; ++k) acc += xb[k] * sw[(p * 64 + k) * 24 + o];
        red[o][p] = acc;
    }
    __syncthreads();
    if (t < 24) {
        float a = sb[t];
        for (int p = 0; p < 8; ++p) a += red[t][p];
        strat[s * 24 + t] = 1.0f / (1.0f + expf(-a));
    }
}

// ---------------- RoPE cos/sin table (double precision) ----------------
__global__ void rope_table_k(float* __restrict__ cost, float* __restrict__ sint) {
    int idx = blockIdx.x * 256 + threadIdx.x;   // 1024*32
    int s = idx >> 5, i = idx & 31;
    double inv = pow(10000.0, -(double)(2 * i) / 64.0);
    double ang = (double)s * inv;
    cost[idx] = (float)cos(ang);
    sint[idx] = (float)sin(ang);
}

// ---------------- RoPE apply to q,k ----------------
__global__ void rope_apply_k(const float* __restrict__ qkv, const float* __restrict__ cost,
                             const float* __restrict__ sint,
                             float* __restrict__ rq, float* __restrict__ rk) {
    int idx = blockIdx.x * 256 + threadIdx.x;   // 1024*8*32 pairs
    int s = idx >> 8;
    int rem = idx & 255;
    int h = rem >> 5, i = rem & 31;
    float c = cost[s * 32 + i], sn = sint[s * 32 + i];
    int qb = s * 1536 + h * 64 + 2 * i;
    float q0 = qkv[qb], q1 = qkv[qb + 1];
    int ob = s * 512 + h * 64 + 2 * i;
    rq[ob]     = q0 * c - q1 * sn;
    rq[ob + 1] = q1 * c + q0 * sn;
    float k0 = qkv[qb + 512], k1 = qkv[qb + 513];
    rk[ob]     = k0 * c - k1 * sn;
    rk[ob + 1] = k1 * c + k0 * sn;
}

// ---------------- build compress-MLP inputs ----------------
__global__ void tkv_k(const float* __restrict__ qkv, const float* __restrict__ k_pos,
                      const float* __restrict__ v_pos,
                      float* __restrict__ tk, float* __restrict__ tv) {
    int idx = blockIdx.x * 256 + threadIdx.x;   // 256*2048
    int row = idx >> 11;          // h*32+nb
    int c = idx & 2047;           // cb*64+d
    int h = row >> 5, nb = row & 31;
    int cb = c >> 6, d = c & 63;
    int srow = nb * 32 + cb;
    tk[idx] = qkv[srow * 1536 + 512 + h * 64 + d] + k_pos[(h * 32 + cb) * 64 + d];
    tv[idx] = qkv[srow * 1536 + 1024 + h * 64 + d] + v_pos[(h * 32 + cb) * 64 + d];
}

// ---------------- f32 GEMM body: 64x64 tile, 256 thr, 4x4 micro, dbuf LDS ----------------
template <bool RELU, bool BIAS>
__device__ __forceinline__ void gemm_body(const float* __restrict__ A, const float* __restrict__ B,
                                          const float* __restrict__ bias, float* __restrict__ C,
                                          int M, int N, int K) {
    __shared__ __align__(16) float As[2][16][68];
    __shared__ __align__(16) float Bs[2][16][64];
    const int bm = blockIdx.x * 64, bn = blockIdx.y * 64;
    const int tid = threadIdx.x;
    const int tx = tid & 15, ty = tid >> 4;
    const int ar = tid >> 2;           // 0..63  A row
    const int ac = (tid & 3) * 4;      // A col within k-step
    const int br = tid >> 4;           // 0..15  B k-row
    const int bc = (tid & 15) * 4;     // B col
    const float* Aptr = A + (size_t)(bm + ar) * K + ac;
    const float* Bptr = B + (size_t)br * N + bn + bc;

    float4 a4 = *(const float4*)(Aptr);
    float4 b4 = *(const float4*)(Bptr);
    float acc[4][4] = {};
    int buf = 0;
    for (int k0 = 0; k0 < K; k0 += 16) {
        As[buf][ac + 0][ar] = a4.x;
        As[buf][ac + 1][ar] = a4.y;
        As[buf][ac + 2][ar] = a4.z;
        As[buf][ac + 3][ar] = a4.w;
        *(float4*)&Bs[buf][br][bc] = b4;
        __syncthreads();
        if (k0 + 16 < K) {
            a4 = *(const float4*)(Aptr + k0 + 16);
            b4 = *(const float4*)(Bptr + (size_t)(k0 + 16) * N);
        }
#pragma unroll
        for (int kk = 0; kk < 16; ++kk) {
            const float4 af = *(const float4*)&As[buf][kk][ty * 4];
            const float4 bf = *(const float4*)&Bs[buf][kk][tx * 4];
            acc[0][0] += af.x * bf.x; acc[0][1] += af.x * bf.y; acc[0][2] += af.x * bf.z; acc[0][3] += af.x * bf.w;
            acc[1][0] += af.y * bf.x; acc[1][1] += af.y * bf.y; acc[1][2] += af.y * bf.z; acc[1][3] += af.y * bf.w;
            acc[2][0] += af.z * bf.x; acc[2][1] += af.z * bf.y; acc[2][2] += af.z * bf.z; acc[2][3] += af.z * bf.w;
            acc[3][0] += af.w * bf.x; acc[3][1] += af.w * bf.y; acc[3][2] += af.w * bf.z; acc[3][3] += af.w * bf.w;
        }
        buf ^= 1;
    }
#pragma unroll
    for (int i = 0; i < 4; ++i) {
        int m = bm + ty * 4 + i;
        float4 v;
        v.x = acc[i][0]; v.y = acc[i][1]; v.z = acc[i][2]; v.w = acc[i][3];
        if (BIAS) {
            v.x += bias[bn + tx * 4 + 0]; v.y += bias[bn + tx * 4 + 1];
            v.z += bias[bn + tx * 4 + 2]; v.w += bias[bn + tx * 4 + 3];
        }
        if (RELU) {
            v.x = fmaxf(v.x, 0.f); v.y = fmaxf(v.y, 0.f);
            v.z = fmaxf(v.z, 0.f); v.w = fmaxf(v.w, 0.f);
        }
        *(float4*)&C[(size_t)m * N + bn + tx * 4] = v;
    }
}

template <bool RELU, bool BIAS>
__global__ void gemm_f32_k(const float* __restrict__ A, const float* __restrict__ B,
                           const float* __restrict__ bias, float* __restrict__ C,
                           int M, int N, int K) {
    gemm_body<RELU, BIAS>(A, B, bias, C, M, N, K);
}

// two independent GEMMs (same shape) in one launch via blockIdx.z
template <bool RELU, bool BIAS>
__global__ void gemm_f32_z2_k(const float* __restrict__ A0, const float* __restrict__ B0,
                              const float* __restrict__ b0, float* __restrict__ C0,
                              const float* __restrict__ A1, const float* __restrict__ B1,
                              const float* __restrict__ b1, float* __restrict__ C1,
                              int M, int N, int K) {
    if (blockIdx.z == 0) gemm_body<RELU, BIAS>(A0, B0, b0, C0, M, N, K);
    else                 gemm_body<RELU, BIAS>(A1, B1, b1, C1, M, N, K);
}

// ---------------- skinny GEMM: C(Mx64) = A(MxK) @ B(Kx64) + bias ----------------
__device__ __forceinline__ void skinny_body(const float* __restrict__ A, const float* __restrict__ B,
                                            const float* __restrict__ bias, float* __restrict__ C, int K) {
    int row = blockIdx.x;
    int col = threadIdx.x & 63;
    int chunk = threadIdx.x >> 6;   // 0..3
    int kpc = K >> 2;               // 512
    const float* a = A + (size_t)row * K + chunk * kpc;
    const float* b = B + (size_t)chunk * kpc * 64;
    float acc = 0.0f;
    for (int k = 0; k < kpc; k += 4) {
        float4 av = *(const float4*)(a + k);
        acc += av.x * b[(k + 0) * 64 + col];
        acc += av.y * b[(k + 1) * 64 + col];
        acc += av.z * b[(k + 2) * 64 + col];
        acc += av.w * b[(k + 3) * 64 + col];
    }
    __shared__ float red[4][64];
    red[chunk][col] = acc;
    __syncthreads();
    if (chunk == 0)
        C[(size_t)row * 64 + col] = red[0][col] + red[1][col] + red[2][col] + red[3][col] + bias[col];
}

__global__ void gemm_skinny_z2_k(const float* __restrict__ A0, const float* __restrict__ B0,
                                 const float* __restrict__ b0, float* __restrict__ C0,
                                 const float* __restrict__ A1, const float* __restrict__ B1,
                                 const float* __restrict__ b1, float* __restrict__ C1, int K) {
    if (blockIdx.z == 0) skinny_body(A0, B0, b0, C0, K);
    else                 skinny_body(A1, B1, b1, C1, K);
}

// ---------------- assemble ck/cv with memory slots ----------------
__global__ void ckfill_k(const float* __restrict__ ckc, const float* __restrict__ cvc,
                         const float* __restrict__ mem_kv,
                         float* __restrict__ ck, float* __restrict__ cv) {
    int idx = blockIdx.x * 256 + threadIdx.x;   // 8*36*64
    if (idx >= 8 * 36 * 64) return;
    int h = idx / (36 * 64);
    int r = (idx >> 6) % 36;
    int d = idx & 63;
    if (r < NMEM) {
        ck[idx] = mem_kv[h * 256 + r * 64 + d];
        cv[idx] = mem_kv[2048 + h * 256 + r * 64 + d];
    } else {
        ck[idx] = ckc[(h * 32 + r - 4) * 64 + d];
        cv[idx] = cvc[(h * 32 + r - 4) * 64 + d];
    }
}

// ---------------- compressed attention + fused top-k ----------------
__global__ void comp_attn_k(const float* __restrict__ qkv, const float* __restrict__ ck,
                            const float* __restrict__ cv, float* __restrict__ c_out,
                            int* __restrict__ sel) {
    int s = blockIdx.x, h = blockIdx.y, lane = threadIdx.x;
    __shared__ __align__(16) float qs[64];
    __shared__ float attns[36];
    qs[lane] = qkv[s * 1536 + h * 64 + lane];
    __syncthreads();
    const float4* qs4 = (const float4*)qs;
    float sim = -FLT_MAX;
    if (lane < 36) {
        bool valid = (lane < NMEM) || ((lane - NMEM + 1) * CB - 1 < s);
        if (valid) {
            const float4* kr4 = (const float4*)(ck + (h * 36 + lane) * 64);
            float acc = 0.0f;
#pragma unroll
            for (int d4 = 0; d4 < 16; ++d4) {
                float4 q = qs4[d4], kv = kr4[d4];
                acc += q.x * kv.x + q.y * kv.y + q.z * kv.z + q.w * kv.w;
            }
            sim = acc * SCALE;
        }
    }
    float mx = sim;
    for (int o = 32; o > 0; o >>= 1) mx = fmaxf(mx, __shfl_xor(mx, o));
    float e = (sim == -FLT_MAX) ? 0.0f : expf(sim - mx);
    float tot = e;
    for (int o = 32; o > 0; o >>= 1) tot += __shfl_xor(tot, o);
    float a = e / tot;
    if (lane < 36) attns[lane] = a;
    __syncthreads();
    float acc = 0.0f;
    for (int j = 0; j < 36; ++j) acc += attns[j] * cv[(h * 36 + j) * 64 + lane];
    c_out[s * 512 + h * 64 + lane] = acc;
    if (lane == 0) {
        float iv[32];
        for (int j = 0; j < 32; ++j) iv[j] = attns[NMEM + j];
        int* sp = sel + (h * 1024 + s) * 8;
        int mask = 0;
        for (int t = 0; t < NSEL; ++t) {
            int bi = 0; float bv = iv[0];
            for (int j = 1; j < 32; ++j) if (iv[j] > bv) { bv = iv[j]; bi = j; }
            sp[t] = bi;
            if (bv > 1e-10f) mask |= 1 << t;
            iv[bi] = -1.0f;
        }
        sp[4] = mask;
    }
}

// ---------------- fine (selected-block) attention ----------------
__global__ void fine_attn_k(const float* __restrict__ qkv, const float* __restrict__ rq,
                            const float* __restrict__ rk, const int* __restrict__ sel,
                            float* __restrict__ f_out) {
    int s = blockIdx.x, h = blockIdx.y, lane = threadIdx.x;
    __shared__ __align__(16) float qs[64];
    __shared__ float attns[160];
    __shared__ int rows[160];
    qs[lane] = rq[s * 512 + h * 64 + lane];
    __syncthreads();
    const float4* qs4 = (const float4*)qs;
    const int* sp = sel + (h * 1024 + s) * 8;
    int own = s >> 5, p = s & 31, mask = sp[4];
    float sims[3]; int rws[3];
    float mx = -FLT_MAX;
    for (int r = 0; r < 3; ++r) {
        int kk = lane + 64 * r;
        sims[r] = -FLT_MAX; rws[r] = 0;
        if (kk < 160) {
            int sl = kk >> 5, t = kk & 31;
            int blk = (sl < 4) ? sp[sl] : own;
            bool valid = (sl < 4) ? ((mask >> sl) & 1) : (t <= p);
            int row = blk * 32 + t;
            rws[r] = row;
            if (valid) {
                const float4* kr4 = (const float4*)(rk + row * 512 + h * 64);
                float acc = 0.0f;
#pragma unroll
                for (int d4 = 0; d4 < 16; ++d4) {
                    float4 q = qs4[d4], kv = kr4[d4];
                    acc += q.x * kv.x + q.y * kv.y + q.z * kv.z + q.w * kv.w;
                }
                sims[r] = acc * SCALE;
            }
        }
        mx = fmaxf(mx, sims[r]);
    }
    for (int o = 32; o > 0; o >>= 1) mx = fmaxf(mx, __shfl_xor(mx, o));
    float lsum = 0.0f, es[3];
    for (int r = 0; r < 3; ++r) {
        es[r] = (sims[r] == -FLT_MAX) ? 0.0f : expf(sims[r] - mx);
        lsum += es[r];
    }
    for (int o = 32; o > 0; o >>= 1) lsum += __shfl_xor(lsum, o);
    for (int r = 0; r < 3; ++r) {
        int kk = lane + 64 * r;
        if (kk < 160) { attns[kk] = es[r] / lsum; rows[kk] = rws[r]; }
    }
    __syncthreads();
    float acc = 0.0f;
    for (int kk = 0; kk < 160; ++kk) {
        float a = attns[kk];
        if (a != 0.0f) acc += a * qkv[rows[kk] * 1536 + 1024 + h * 64 + lane];
    }
    f_out[s * 512 + h * 64 + lane] = acc;
}

// ---------------- sliding-window attention ----------------
__global__ void slide_attn_k(const float* __restrict__ qkv, const float* __restrict__ rq,
                             const float* __restrict__ rk, float* __restrict__ s_out) {
    int s = blockIdx.x, h = blockIdx.y, lane = threadIdx.x;
    __shared__ __align__(16) float qs[64];
    __shared__ float attns[65];
    qs[lane] = rq[s * 512 + h * 64 + lane];
    __syncthreads();
    const float4* qs4 = (const float4*)qs;
    int lo = (s > WIN) ? s - WIN : 0;
    int cnt = s - lo + 1;   // <= 65
    float sims[2];
    float mx = -FLT_MAX;
    for (int r = 0; r < 2; ++r) {
        int kk = lane + 64 * r;
        sims[r] = -FLT_MAX;
        if (kk < cnt) {
            const float4* kr4 = (const float4*)(rk + (lo + kk) * 512 + h * 64);
            float acc = 0.0f;
#pragma unroll
            for (int d4 = 0; d4 < 16; ++d4) {
                float4 q = qs4[d4], kv = kr4[d4];
                acc += q.x * kv.x + q.y * kv.y + q.z * kv.z + q.w * kv.w;
            }
            sims[r] = acc * SCALE;
        }
        mx = fmaxf(mx, sims[r]);
    }
    for (int o = 32; o > 0; o >>= 1) mx = fmaxf(mx, __shfl_xor(mx, o));
    float lsum = 0.0f, es[2];
    for (int r = 0; r < 2; ++r) {
        es[r] = (sims[r] == -FLT_MAX) ? 0.0f : expf(sims[r] - mx);
        lsum += es[r];
    }
    for (int o = 32; o > 0; o >>= 1) lsum += __shfl_xor(lsum, o);
    for (int r = 0; r < 2; ++r) {
        int kk = lane + 64 * r;
        if (kk < 65) attns[kk] = (kk < cnt) ? es[r] / lsum : 0.0f;
    }
    __syncthreads();
    float acc = 0.0f;
    for (int kk = 0; kk < cnt; ++kk)
        acc += attns[kk] * qkv[(lo + kk) * 1536 + 1024 + h * 64 + lane];
    s_out[s * 512 + h * 64 + lane] = acc;
}

// ---------------- gated combine ----------------
__global__ void combine_k(const float* __restrict__ c_out, const float* __restrict__ f_out,
                          const float* __restrict__ s_out, const float* __restrict__ strat,
                          float* __restrict__ att) {
    int idx = blockIdx.x * 256 + threadIdx.x;   // 1024*512
    int s = idx >> 9;
    int c = idx & 511;
    int h = c >> 6;
    const float* st = strat + s * 24 + h * 3;
    att[idx] = st[0] * c_out[idx] + st[1] * f_out[idx] + st[2] * s_out[idx];
}

extern "C" void kernel_launch(void* const* d_in, const int* in_sizes, int n_in,
                              void* d_out, int out_size, void* d_ws, size_t ws_size,
                              hipStream_t stream) {
    const float* inp     = (const float*)d_in[0];
    const float* norm_g  = (const float*)d_in[1];
    const float* w_qkv   = (const float*)d_in[2];
    const float* k_pos   = (const float*)d_in[3];
    const float* v_pos   = (const float*)d_in[4];
    const float* kc_w1   = (const float*)d_in[5];
    const float* kc_b1   = (const float*)d_in[6];
    const float* kc_w2   = (const float*)d_in[7];
    const float* kc_b2   = (const float*)d_in[8];
    const float* vc_w1   = (const float*)d_in[9];
    const float* vc_b1   = (const float*)d_in[10];
    const float* vc_w2   = (const float*)d_in[11];
    const float* vc_b2   = (const float*)d_in[12];
    const float* mem_kv  = (const float*)d_in[13];
    const float* strat_w = (const float*)d_in[14];
    const float* strat_b = (const float*)d_in[15];
    const float* out_w   = (const float*)d_in[16];
    float* out = (float*)d_out;

    float* ws = (float*)d_ws;
    float* x     = ws + OFF_X;
    float* qkv   = ws + OFF_QKV;
    float* rq    = ws + OFF_RQ;
    float* rk    = ws + OFF_RK;
    float* cost  = ws + OFF_COS;
    float* sint  = ws + OFF_SIN;
    float* tk    = ws + OFF_TK;
    float* tv    = ws + OFF_TV;
    float* hk    = ws + OFF_HK;
    float* hv    = ws + OFF_HV;
    float* ckc   = ws + OFF_CKC;
    float* cvc   = ws + OFF_CVC;
    float* ck    = ws + OFF_CK;
    float* cv    = ws + OFF_CV;
    float* c_out = ws + OFF_COUT;
    float* f_out = ws + OFF_FOUT;
    float* s_out = ws + OFF_SOUT;
    float* strat = ws + OFF_STRAT;
    float* att   = ws + OFF_ATT;
    int*   sel   = (int*)(ws + OFF_SEL);

    rmsnorm_strat_k<<<1024, 256, 0, stream>>>(inp, norm_g, strat_w, strat_b, x, strat);
    rope_table_k<<<128, 256, 0, stream>>>(cost, sint);
    gemm_f32_k<false, false><<<dim3(16, 24), 256, 0, stream>>>(x, w_qkv, nullptr, qkv, 1024, 1536, 512);
    rope_apply_k<<<1024, 256, 0, stream>>>(qkv, cost, sint, rq, rk);
    tkv_k<<<2048, 256, 0, stream>>>(qkv, k_pos, v_pos, tk, tv);
    gemm_f32_z2_k<true, true><<<dim3(4, 32, 2), 256, 0, stream>>>(
        tk, kc_w1, kc_b1, hk, tv, vc_w1, vc_b1, hv, 256, 2048, 2048);
    gemm_skinny_z2_k<<<dim3(256, 1, 2), 256, 0, stream>>>(
        hk, kc_w2, kc_b2, ckc, hv, vc_w2, vc_b2, cvc, 2048);
    ckfill_k<<<72, 256, 0, stream>>>(ckc, cvc, mem_kv, ck, cv);
    comp_attn_k<<<dim3(1024, 8), 64, 0, stream>>>(qkv, ck, cv, c_out, sel);
    fine_attn_k<<<dim3(1024, 8), 64, 0, stream>>>(qkv, rq, rk, sel, f_out);
    slide_attn_k<<<dim3(1024, 8), 64, 0, stream>>>(qkv, rq, rk, s_out);
    combine_k<<<2048, 256, 0, stream>>>(c_out, f_out, s_out, strat, att);
    gemm_f32_k<false, false><<<dim3(16, 8), 256, 0, stream>>>(att, out_w, nullptr, out, 1024, 512, 512);
}

// Round 3
// 375.384 us; speedup vs baseline: 3.2798x; 1.2139x over previous
//
#include <hip/hip_runtime.h>
#include <hip/hip_bf16.h>
#include <cfloat>
#include <math.h>

// Problem constants
#define S_LEN 1024
#define DIM 512
#define H_N 8
#define DH 64
#define CB 32
#define NB 32
#define NSEL 4
#define NMEM 4
#define WIN 64
#define SCALE 0.125f
#define EPS 1.1920929e-07f

// ---------------- ws layout (float offsets) ----------------
// QKVP overlaps [RQ..HV) (those are written only after qkv reduce).
// OUTP overlaps COMPP (comp partials dead before out GEMM).
#define OFF_X      0u
#define OFF_QKV    524288u     // 1024*1536
#define OFF_RQ     2097152u
#define OFF_RK     2621440u
#define OFF_COS    3145728u
#define OFF_SIN    3178496u
#define OFF_TK     3211264u
#define OFF_TV     3735552u
#define OFF_HK     4259840u
#define OFF_HV     4784128u
#define OFF_CKC    5308416u    // 256*64
#define OFF_CVC    5324800u
#define OFF_STRAT  5341184u    // 1024*24
#define OFF_ATT    5365760u    // 1024*512
#define OFF_QKVP   2097152u    // 2 x 1024*1536 partials (overlap RQ..HV)
#define OFF_COMPP  5890048u    // 8 x 256*2048 partials
#define OFF_OUTP   5890048u    // 4 x 1024*512 partials (reuse COMPP)
// total: 10084352 floats = 40.3 MB

// ---------------- RMSNorm + strategy gates (fused) ----------------
__global__ void rmsnorm_strat_k(const float* __restrict__ inp, const float* __restrict__ g,
                                const float* __restrict__ sw, const float* __restrict__ sb,
                                float* __restrict__ x, float* __restrict__ strat) {
    int s = blockIdx.x;
    int t = threadIdx.x;
    __shared__ __align__(16) float xs[512];
    __shared__ float red[24][8];
    float v0 = inp[s * DIM + t];
    float v1 = inp[s * DIM + t + 256];
    float ss = v0 * v0 + v1 * v1;
    for (int o = 32; o > 0; o >>= 1) ss += __shfl_xor(ss, o);
    __shared__ float wsum[4];
    int wid = t >> 6, lane = t & 63;
    if (lane == 0) wsum[wid] = ss;
    __syncthreads();
    float tot = wsum[0] + wsum[1] + wsum[2] + wsum[3];
    float scale = 1.0f / sqrtf(tot / (float)DIM + EPS);
    float x0 = v0 * scale * g[t];
    float x1 = v1 * scale * g[t + 256];
    x[s * DIM + t]       = x0;
    x[s * DIM + t + 256] = x1;
    xs[t] = x0;
    xs[t + 256] = x1;
    __syncthreads();
    if (t < 192) {
        int o = t >> 3, p = t & 7;
        float acc = 0.0f;
        const float* xb = xs + p * 64;
        for (int k = 0; k < 64; ++k) acc += xb[k] * sw[(p * 64 + k) * 24 + o];
        red[o][p] = acc;
    }
    __syncthreads();
    if (t < 24) {
        float a = sb[t];
        for (int p = 0; p < 8; ++p) a += red[t][p];
        strat[s * 24 + t] = 1.0f / (1.0f + expf(-a));
    }
}

// ---------------- RoPE cos/sin table ----------------
__global__ void rope_table_k(float* __restrict__ cost, float* __restrict__ sint) {
    int idx = blockIdx.x * 256 + threadIdx.x;   // 1024*32
    int s = idx >> 5, i = idx & 31;
    double inv = pow(10000.0, -(double)(2 * i) / 64.0);
    double ang = (double)s * inv;
    cost[idx] = (float)cos(ang);
    sint[idx] = (float)sin(ang);
}

// ---------------- RoPE apply to q,k ----------------
__global__ void rope_apply_k(const float* __restrict__ qkv, const float* __restrict__ cost,
                             const float* __restrict__ sint,
                             float* __restrict__ rq, float* __restrict__ rk) {
    int idx = blockIdx.x * 256 + threadIdx.x;   // 1024*8*32 pairs
    int s = idx >> 8;
    int rem = idx & 255;
    int h = rem >> 5, i = rem & 31;
    float c = cost[s * 32 + i], sn = sint[s * 32 + i];
    int qb = s * 1536 + h * 64 + 2 * i;
    float q0 = qkv[qb], q1 = qkv[qb + 1];
    int ob = s * 512 + h * 64 + 2 * i;
    rq[ob]     = q0 * c - q1 * sn;
    rq[ob + 1] = q1 * c + q0 * sn;
    float k0 = qkv[qb + 512], k1 = qkv[qb + 513];
    rk[ob]     = k0 * c - k1 * sn;
    rk[ob + 1] = k1 * c + k0 * sn;
}

// ---------------- build compress-MLP inputs ----------------
__global__ void tkv_k(const float* __restrict__ qkv, const float* __restrict__ k_pos,
                      const float* __restrict__ v_pos,
                      float* __restrict__ tk, float* __restrict__ tv) {
    int idx = blockIdx.x * 256 + threadIdx.x;   // 256*2048
    int row = idx >> 11;
    int c = idx & 2047;
    int h = row >> 5, nb = row & 31;
    int cb = c >> 6, d = c & 63;
    int srow = nb * 32 + cb;
    tk[idx] = qkv[srow * 1536 + 512 + h * 64 + d] + k_pos[(h * 32 + cb) * 64 + d];
    tv[idx] = qkv[srow * 1536 + 1024 + h * 64 + d] + v_pos[(h * 32 + cb) * 64 + d];
}

// ---------------- f32 GEMM 64x64 tile, split-K partial writer ----------------
__device__ __forceinline__ void gemm_sk_body(const float* __restrict__ A, const float* __restrict__ B,
                                             float* __restrict__ P, int M, int N, int K,
                                             int kstart, int Ks) {
    __shared__ __align__(16) float As[2][16][68];
    __shared__ __align__(16) float Bs[2][16][64];
    const int bm = blockIdx.x * 64, bn = blockIdx.y * 64;
    const int tid = threadIdx.x;
    const int tx = tid & 15, ty = tid >> 4;
    const int ar = tid >> 2;
    const int ac = (tid & 3) * 4;
    const int br = tid >> 4;
    const int bc = (tid & 15) * 4;
    const float* Aptr = A + (size_t)(bm + ar) * K + kstart + ac;
    const float* Bptr = B + (size_t)(kstart + br) * N + bn + bc;

    float4 a4 = *(const float4*)(Aptr);
    float4 b4 = *(const float4*)(Bptr);
    float acc[4][4] = {};
    int buf = 0;
    for (int k0 = 0; k0 < Ks; k0 += 16) {
        As[buf][ac + 0][ar] = a4.x;
        As[buf][ac + 1][ar] = a4.y;
        As[buf][ac + 2][ar] = a4.z;
        As[buf][ac + 3][ar] = a4.w;
        *(float4*)&Bs[buf][br][bc] = b4;
        __syncthreads();
        if (k0 + 16 < Ks) {
            a4 = *(const float4*)(Aptr + k0 + 16);
            b4 = *(const float4*)(Bptr + (size_t)(k0 + 16) * N);
        }
#pragma unroll
        for (int kk = 0; kk < 16; ++kk) {
            const float4 af = *(const float4*)&As[buf][kk][ty * 4];
            const float4 bf = *(const float4*)&Bs[buf][kk][tx * 4];
            acc[0][0] += af.x * bf.x; acc[0][1] += af.x * bf.y; acc[0][2] += af.x * bf.z; acc[0][3] += af.x * bf.w;
            acc[1][0] += af.y * bf.x; acc[1][1] += af.y * bf.y; acc[1][2] += af.y * bf.z; acc[1][3] += af.y * bf.w;
            acc[2][0] += af.z * bf.x; acc[2][1] += af.z * bf.y; acc[2][2] += af.z * bf.z; acc[2][3] += af.z * bf.w;
            acc[3][0] += af.w * bf.x; acc[3][1] += af.w * bf.y; acc[3][2] += af.w * bf.z; acc[3][3] += af.w * bf.w;
        }
        buf ^= 1;
    }
#pragma unroll
    for (int i = 0; i < 4; ++i) {
        int m = bm + ty * 4 + i;
        float4 v;
        v.x = acc[i][0]; v.y = acc[i][1]; v.z = acc[i][2]; v.w = acc[i][3];
        *(float4*)&P[(size_t)m * N + bn + tx * 4] = v;
    }
}

// qkv / out GEMM: blockIdx.z = K-split
__global__ void gemm_sk_k(const float* __restrict__ A, const float* __restrict__ B,
                          float* __restrict__ P, int M, int N, int K, int nsplit) {
    int kz = blockIdx.z;
    int Ks = K / nsplit;
    gemm_sk_body(A, B, P + (size_t)kz * M * N, M, N, K, kz * Ks, Ks);
}

// comp pair: blockIdx.z in [0,8): g = z>>2 selects gemm, kz = z&3 the K-split
__global__ void gemm_comp_k(const float* __restrict__ A0, const float* __restrict__ B0,
                            const float* __restrict__ A1, const float* __restrict__ B1,
                            float* __restrict__ P, int M, int N, int K) {
    int z = blockIdx.z;
    int g = z >> 2, kz = z & 3;
    const float* A = g ? A1 : A0;
    const float* B = g ? B1 : B0;
    int Ks = K >> 2;
    gemm_sk_body(A, B, P + (size_t)z * M * N, M, N, K, kz * Ks, Ks);
}

// ---------------- split-K reduce (+bias,+relu) ----------------
template <int NS, bool RELU, bool BIAS>
__global__ void reduce_k(const float* __restrict__ P, const float* __restrict__ bias,
                         float* __restrict__ Y, int MN, int N) {
    int idx4 = blockIdx.x * 256 + threadIdx.x;
    if (idx4 * 4 >= MN) return;
    const float4* p4 = (const float4*)P;
    int mn4 = MN >> 2;
    float4 v = p4[idx4];
#pragma unroll
    for (int j = 1; j < NS; ++j) {
        float4 w = p4[idx4 + j * (size_t)mn4];
        v.x += w.x; v.y += w.y; v.z += w.z; v.w += w.w;
    }
    if (BIAS) {
        int col = (idx4 * 4) % N;
        float4 b = *(const float4*)(bias + col);
        v.x += b.x; v.y += b.y; v.z += b.z; v.w += b.w;
    }
    if (RELU) {
        v.x = fmaxf(v.x, 0.f); v.y = fmaxf(v.y, 0.f);
        v.z = fmaxf(v.z, 0.f); v.w = fmaxf(v.w, 0.f);
    }
    ((float4*)Y)[idx4] = v;
}

// ---------------- skinny GEMM: C(Mx64) = A(MxK) @ B(Kx64) + bias ----------------
__device__ __forceinline__ void skinny_body(const float* __restrict__ A, const float* __restrict__ B,
                                            const float* __restrict__ bias, float* __restrict__ C, int K) {
    int row = blockIdx.x;
    int col = threadIdx.x & 63;
    int chunk = threadIdx.x >> 6;
    int kpc = K >> 2;
    const float* a = A + (size_t)row * K + chunk * kpc;
    const float* b = B + (size_t)chunk * kpc * 64;
    float acc = 0.0f;
    for (int k = 0; k < kpc; k += 4) {
        float4 av = *(const float4*)(a + k);
        acc += av.x * b[(k + 0) * 64 + col];
        acc += av.y * b[(k + 1) * 64 + col];
        acc += av.z * b[(k + 2) * 64 + col];
        acc += av.w * b[(k + 3) * 64 + col];
    }
    __shared__ float red[4][64];
    red[chunk][col] = acc;
    __syncthreads();
    if (chunk == 0)
        C[(size_t)row * 64 + col] = red[0][col] + red[1][col] + red[2][col] + red[3][col] + bias[col];
}

__global__ void gemm_skinny_z2_k(const float* __restrict__ A0, const float* __restrict__ B0,
                                 const float* __restrict__ b0, float* __restrict__ C0,
                                 const float* __restrict__ A1, const float* __restrict__ B1,
                                 const float* __restrict__ b1, float* __restrict__ C1, int K) {
    if (blockIdx.z == 0) skinny_body(A0, B0, b0, C0, K);
    else                 skinny_body(A1, B1, b1, C1, K);
}

// ---------------- helpers for fused attention ----------------
__device__ __forceinline__ float dot64(const float* __restrict__ qsh, const float* __restrict__ kr) {
    const float4* q4 = (const float4*)qsh;
    const float4* k4 = (const float4*)kr;
    float acc = 0.0f;
#pragma unroll
    for (int i = 0; i < 16; ++i) {
        float4 q = q4[i], k = k4[i];
        acc += q.x * k.x + q.y * k.y + q.z * k.z + q.w * k.w;
    }
    return acc;
}

__device__ __forceinline__ float redmax64(float v) {
    for (int o = 32; o > 0; o >>= 1) v = fmaxf(v, __shfl_xor(v, o));
    return v;
}
__device__ __forceinline__ float redsum64(float v) {
    for (int o = 32; o > 0; o >>= 1) v += __shfl_xor(v, o);
    return v;
}

// ---------------- fused attention: comp + topk + fine + slide + gates ----------------
// one 64-thread block per (s, h)
__global__ void attn_fused_k(const float* __restrict__ qkv, const float* __restrict__ rq,
                             const float* __restrict__ rk, const float* __restrict__ ckc,
                             const float* __restrict__ cvc, const float* __restrict__ mem_kv,
                             const float* __restrict__ strat, float* __restrict__ att) {
    int s = blockIdx.x, h = blockIdx.y, lane = threadIdx.x;
    __shared__ __align__(16) float qs[64];
    __shared__ __align__(16) float rqs[64];
    __shared__ float pa[192];
    __shared__ int rows[192];
    qs[lane]  = qkv[s * 1536 + h * 64 + lane];
    rqs[lane] = rq[s * 512 + h * 64 + lane];
    __syncthreads();

    // ---- compressed attention (36 keys: 4 mem + 32 comp blocks) ----
    float sim = -FLT_MAX;
    if (lane < 36) {
        bool valid = (lane < NMEM) || ((lane - NMEM + 1) * CB - 1 < s);
        if (valid) {
            const float* kr = (lane < NMEM) ? (mem_kv + (h * 4 + lane) * 64)
                                            : (ckc + (h * 32 + lane - NMEM) * 64);
            sim = dot64(qs, kr) * SCALE;
        }
    }
    float mx = redmax64(sim);
    float e = (sim == -FLT_MAX) ? 0.0f : expf(sim - mx);
    float tot = redsum64(e);
    float a = e / tot;
    pa[lane] = (lane < 36) ? a : 0.0f;
    __syncthreads();
    float c_acc = 0.0f;
    for (int j = 0; j < NMEM; ++j)
        c_acc += pa[j] * mem_kv[2048 + (h * 4 + j) * 64 + lane];
    for (int j = 0; j < 32; ++j)
        c_acc += pa[NMEM + j] * cvc[(h * 32 + j) * 64 + lane];

    // ---- top-4 of comp attn (wave-parallel, lowest-index tie-break) ----
    float tval = (lane >= NMEM && lane < 36) ? a : -1.0f;
    int tidx = lane - NMEM;
    int sel0, sel1, sel2, sel3, msk = 0;
#pragma unroll
    for (int t = 0; t < NSEL; ++t) {
        float bv = tval; int bi = tidx;
        for (int o = 32; o > 0; o >>= 1) {
            float ov = __shfl_xor(bv, o);
            int oi = __shfl_xor(bi, o);
            if (ov > bv || (ov == bv && oi < bi)) { bv = ov; bi = oi; }
        }
        if (t == 0) sel0 = bi; else if (t == 1) sel1 = bi;
        else if (t == 2) sel2 = bi; else sel3 = bi;
        if (bv > 1e-10f) msk |= 1 << t;
        if (tidx == bi && lane >= NMEM && lane < 36) tval = -1.0f;
    }

    // ---- fine attention over 5*32 = 160 keys ----
    int own = s >> 5, p = s & 31, t31 = lane & 31;
    bool hi = lane >= 32;
    // seg A: slots 0,1
    int blkA = hi ? sel1 : sel0;
    bool valA = hi ? (msk & 2) : (msk & 1);
    int rowA = blkA * 32 + t31;
    float simA = valA ? dot64(rqs, rk + rowA * 512 + h * 64) * SCALE : -FLT_MAX;
    // seg B: slots 2,3
    int blkB = hi ? sel3 : sel2;
    bool valB = hi ? (msk & 8) : (msk & 4);
    int rowB = blkB * 32 + t31;
    float simB = valB ? dot64(rqs, rk + rowB * 512 + h * 64) * SCALE : -FLT_MAX;
    // seg C: own block (lanes 0..31 only)
    int rowC = own * 32 + t31;
    bool valC = (!hi) && (t31 <= p);
    float simC = valC ? dot64(rqs, rk + rowC * 512 + h * 64) * SCALE : -FLT_MAX;

    float fmx = redmax64(fmaxf(fmaxf(simA, simB), simC));
    float eA = (simA == -FLT_MAX) ? 0.0f : expf(simA - fmx);
    float eB = (simB == -FLT_MAX) ? 0.0f : expf(simB - fmx);
    float eC = (simC == -FLT_MAX) ? 0.0f : expf(simC - fmx);
    float fsum = redsum64(eA + eB + eC);
    float finv = 1.0f / fsum;
    pa[lane] = eA * finv;        rows[lane] = rowA;
    pa[64 + lane] = eB * finv;   rows[64 + lane] = rowB;
    pa[128 + lane] = eC * finv;  rows[128 + lane] = rowC;
    __syncthreads();
    float f_acc = 0.0f;
    for (int kk = 0; kk < 160; ++kk)
        f_acc += pa[kk] * qkv[rows[kk] * 1536 + 1024 + h * 64 + lane];
    __syncthreads();

    // ---- sliding-window attention ----
    int lo = (s > WIN) ? s - WIN : 0;
    int cnt = s - lo + 1;   // <= 65
    float sA = (lane < cnt) ? dot64(rqs, rk + (lo + lane) * 512 + h * 64) * SCALE : -FLT_MAX;
    float sB = (64 + lane < cnt) ? dot64(rqs, rk + (lo + 64 + lane) * 512 + h * 64) * SCALE : -FLT_MAX;
    float smx = redmax64(fmaxf(sA, sB));
    float esA = (sA == -FLT_MAX) ? 0.0f : expf(sA - smx);
    float esB = (sB == -FLT_MAX) ? 0.0f : expf(sB - smx);
    float ssum = redsum64(esA + esB);
    float sinv = 1.0f / ssum;
    pa[lane] = esA * sinv;
    if (64 + lane < cnt) pa[64 + lane] = esB * sinv;
    __syncthreads();
    float s_acc = 0.0f;
    for (int kk = 0; kk < cnt; ++kk)
        s_acc += pa[kk] * qkv[(lo + kk) * 1536 + 1024 + h * 64 + lane];

    // ---- gated combine ----
    const float* st = strat + s * 24 + h * 3;
    att[s * 512 + h * 64 + lane] = st[0] * c_acc + st[1] * f_acc + st[2] * s_acc;
}

extern "C" void kernel_launch(void* const* d_in, const int* in_sizes, int n_in,
                              void* d_out, int out_size, void* d_ws, size_t ws_size,
                              hipStream_t stream) {
    const float* inp     = (const float*)d_in[0];
    const float* norm_g  = (const float*)d_in[1];
    const float* w_qkv   = (const float*)d_in[2];
    const float* k_pos   = (const float*)d_in[3];
    const float* v_pos   = (const float*)d_in[4];
    const float* kc_w1   = (const float*)d_in[5];
    const float* kc_b1   = (const float*)d_in[6];
    const float* kc_w2   = (const float*)d_in[7];
    const float* kc_b2   = (const float*)d_in[8];
    const float* vc_w1   = (const float*)d_in[9];
    const float* vc_b1   = (const float*)d_in[10];
    const float* vc_w2   = (const float*)d_in[11];
    const float* vc_b2   = (const float*)d_in[12];
    const float* mem_kv  = (const float*)d_in[13];
    const float* strat_w = (const float*)d_in[14];
    const float* strat_b = (const float*)d_in[15];
    const float* out_w   = (const float*)d_in[16];
    float* out = (float*)d_out;

    float* ws = (float*)d_ws;
    float* x     = ws + OFF_X;
    float* qkv   = ws + OFF_QKV;
    float* rq    = ws + OFF_RQ;
    float* rk    = ws + OFF_RK;
    float* cost  = ws + OFF_COS;
    float* sint  = ws + OFF_SIN;
    float* tk    = ws + OFF_TK;
    float* tv    = ws + OFF_TV;
    float* hk    = ws + OFF_HK;
    float* hv    = ws + OFF_HV;
    float* ckc   = ws + OFF_CKC;
    float* cvc   = ws + OFF_CVC;
    float* strat = ws + OFF_STRAT;
    float* att   = ws + OFF_ATT;
    float* qkvp  = ws + OFF_QKVP;
    float* compp = ws + OFF_COMPP;
    float* outp  = ws + OFF_OUTP;

    // 1. rmsnorm + strat gates
    rmsnorm_strat_k<<<1024, 256, 0, stream>>>(inp, norm_g, strat_w, strat_b, x, strat);
    // 2. qkv projection (split-K=2) + reduce
    gemm_sk_k<<<dim3(16, 24, 2), 256, 0, stream>>>(x, w_qkv, qkvp, 1024, 1536, 512, 2);
    reduce_k<2, false, false><<<1536, 256, 0, stream>>>(qkvp, nullptr, qkv, 1024 * 1536, 1536);
    // 3. rope + comp-MLP inputs (these overwrite the dead qkvp region)
    rope_table_k<<<128, 256, 0, stream>>>(cost, sint);
    rope_apply_k<<<1024, 256, 0, stream>>>(qkv, cost, sint, rq, rk);
    tkv_k<<<2048, 256, 0, stream>>>(qkv, k_pos, v_pos, tk, tv);
    // 4. comp MLP layer-1 (two GEMMs x split-K=4) + reduce(bias,relu)
    gemm_comp_k<<<dim3(4, 32, 8), 256, 0, stream>>>(tk, kc_w1, tv, vc_w1, compp, 256, 2048, 2048);
    reduce_k<4, true, true><<<512, 256, 0, stream>>>(compp, kc_b1, hk, 256 * 2048, 2048);
    reduce_k<4, true, true><<<512, 256, 0, stream>>>(compp + 4u * 256 * 2048, vc_b1, hv, 256 * 2048, 2048);
    // 5. comp MLP layer-2 (skinny)
    gemm_skinny_z2_k<<<dim3(256, 1, 2), 256, 0, stream>>>(hk, kc_w2, kc_b2, ckc, hv, vc_w2, vc_b2, cvc, 2048);
    // 6. fused attention (comp + topk + fine + slide + gates)
    attn_fused_k<<<dim3(1024, 8), 64, 0, stream>>>(qkv, rq, rk, ckc, cvc, mem_kv, strat, att);
    // 7. output projection (split-K=4) + reduce
    gemm_sk_k<<<dim3(16, 8, 4), 256, 0, stream>>>(att, out_w, outp, 1024, 512, 512, 4);
    reduce_k<4, false, false><<<512, 256, 0, stream>>>(outp, nullptr, out, 1024 * 512, 512);
}